// Round 1
// baseline (102527.136 us; speedup 1.0000x reference)
//
#include <hip/hip_runtime.h>

#define N_PTS 40000
#define C_IN 64
#define C_OUT 128
#define K_NN 16
#define M_SAMPLES 10001   // int(40000*0.25)+1

// ---------------- FPS ----------------
#define FPS_THREADS 512
#define FPS_PPT 79                       // ceil(40000/512)
#define FPS_PAD (FPS_THREADS * FPS_PPT)  // 40448

// Exact reference arithmetic: (dx*dx + dy*dy) + dz*dz, no FMA contraction.
__device__ __forceinline__ float dist3_exact(float dx, float dy, float dz) {
#pragma clang fp contract(off)
  return (dx * dx + dy * dy) + dz * dz;
}

__global__ __launch_bounds__(FPS_THREADS) void fps_kernel(
    const float* __restrict__ xyz, float* __restrict__ nxyz_out) {
  __shared__ float dist_s[FPS_PAD];       // 161792 B
  __shared__ float red_v[2][FPS_THREADS / 64];
  __shared__ int   red_i[2][FPS_THREADS / 64];

  const int t = threadIdx.x;

  // Load my points into registers (persist across all iterations)
  float px[FPS_PPT], py[FPS_PPT], pz[FPS_PPT];
#pragma unroll
  for (int j = 0; j < FPS_PPT; ++j) {
    int p = j * FPS_THREADS + t;
    int pc = (p < N_PTS) ? p : (N_PTS - 1);
    px[j] = xyz[3 * pc + 0];
    py[j] = xyz[3 * pc + 1];
    pz[j] = xyz[3 * pc + 2];
    dist_s[p] = (p < N_PTS) ? 1e10f : -1.0f;  // pad slots can never win
  }
  // First center is point 0 (reference starts at last_idx=0)
  float lx = xyz[0], ly = xyz[1], lz = xyz[2];
  __syncthreads();

  for (int s = 0; s < M_SAMPLES; ++s) {
    if (t == 0) {
      // n_xyz[s] = exact coords of current center
      nxyz_out[3 * s + 0] = lx;
      nxyz_out[3 * s + 1] = ly;
      nxyz_out[3 * s + 2] = lz;
    }
    // min-update all my points with dist to current center; track local argmax
    float bv = -2.0f;
    int bi = 0x7fffffff;
#pragma unroll
    for (int j = 0; j < FPS_PPT; ++j) {
      int p = j * FPS_THREADS + t;
      float dx, dy, dz;
      {
#pragma clang fp contract(off)
        dx = px[j] - lx;
        dy = py[j] - ly;
        dz = pz[j] - lz;
      }
      float d = dist3_exact(dx, dy, dz);
      float od = dist_s[p];
      float nd = fminf(od, d);        // jnp.minimum semantics (no NaNs)
      dist_s[p] = nd;
      // strict > keeps lowest index (j ascending => p ascending per thread)
      if (nd > bv) { bv = nd; bi = p; }
    }
    // wave-level argmax with first-index tie-break
#pragma unroll
    for (int off = 32; off > 0; off >>= 1) {
      float ov = __shfl_down(bv, off);
      int oi = __shfl_down(bi, off);
      if (ov > bv || (ov == bv && oi < bi)) { bv = ov; bi = oi; }
    }
    const int par = s & 1;  // parity double-buffer: lets us use ONE barrier/iter
    if ((t & 63) == 0) {
      red_v[par][t >> 6] = bv;
      red_i[par][t >> 6] = bi;
    }
    __syncthreads();
    // all threads redundantly reduce the per-wave candidates
    bv = red_v[par][0];
    bi = red_i[par][0];
#pragma unroll
    for (int w = 1; w < FPS_THREADS / 64; ++w) {
      float ov = red_v[par][w];
      int oi = red_i[par][w];
      if (ov > bv || (ov == bv && oi < bi)) { bv = ov; bi = oi; }
    }
    // next center: all lanes load same address (single cacheline, L2-hot)
    lx = xyz[3 * bi + 0];
    ly = xyz[3 * bi + 1];
    lz = xyz[3 * bi + 2];
  }
}

// ---------------- KNN: one wave per center ----------------
#define KNN_TILE 2048

__device__ __forceinline__ float knn_dist_exact(float sn, float cx, float cy,
                                                float cz, float x, float y,
                                                float z) {
#pragma clang fp contract(off)
  float sx = (x * x + y * y) + z * z;
  float dot = (cx * x + cy * y) + cz * z;
  return (sn - 2.0f * dot) + sx;   // matches  sn - 2*(n@x) + sx
}

__global__ __launch_bounds__(256) void knn_kernel(
    const float* __restrict__ xyz, const float* __restrict__ nxyz,
    int* __restrict__ knn_out) {
  __shared__ float txyz[KNN_TILE * 3];  // 24 KB
  const int lane = threadIdx.x & 63;
  const int wv = threadIdx.x >> 6;
  const int m = blockIdx.x * 4 + wv;
  const bool active = (m < M_SAMPLES);

  float cx = 0.f, cy = 0.f, cz = 0.f;
  if (active) {
    cx = nxyz[3 * m + 0];
    cy = nxyz[3 * m + 1];
    cz = nxyz[3 * m + 2];
  }
  float sn;
  {
#pragma clang fp contract(off)
    sn = (cx * cx + cy * cy) + cz * cz;
  }

  // per-lane sorted top-16 by (dist, idx) lexicographic (matches top_k ties)
  float hd[K_NN];
  int hi[K_NN];
#pragma unroll
  for (int i = 0; i < K_NN; ++i) { hd[i] = 3.4e38f; hi[i] = 0x7fffffff; }

  for (int base = 0; base < N_PTS; base += KNN_TILE) {
    const int cnt = min(KNN_TILE, N_PTS - base);
    __syncthreads();
    {  // cooperative vectorized tile load (cnt*3 divisible by 4 here)
      const float4* src4 = (const float4*)(xyz + (size_t)base * 3);
      float4* dst4 = (float4*)txyz;
      const int n4 = (cnt * 3) >> 2;
      for (int i = threadIdx.x; i < n4; i += 256) dst4[i] = src4[i];
    }
    __syncthreads();
    for (int p = lane; p < cnt; p += 64) {
      float x = txyz[3 * p + 0], y = txyz[3 * p + 1], z = txyz[3 * p + 2];
      float d = knn_dist_exact(sn, cx, cy, cz, x, y, z);
      int gi = base + p;
      if (d < hd[K_NN - 1] || (d == hd[K_NN - 1] && gi < hi[K_NN - 1])) {
        hd[K_NN - 1] = d;
        hi[K_NN - 1] = gi;
#pragma unroll
        for (int i = K_NN - 1; i > 0; --i) {
          bool sw = (hd[i] < hd[i - 1]) ||
                    (hd[i] == hd[i - 1] && hi[i] < hi[i - 1]);
          if (sw) {
            float td = hd[i]; hd[i] = hd[i - 1]; hd[i - 1] = td;
            int ti = hi[i]; hi[i] = hi[i - 1]; hi[i - 1] = ti;
          }
        }
      }
    }
  }

  // merge 64 sorted lists: 16 rounds of wave-argmin + pop
  int keep = 0;
#pragma unroll 1
  for (int r = 0; r < K_NN; ++r) {
    float d0 = hd[0];
    int i0 = hi[0];
    int l0 = lane;
#pragma unroll
    for (int off = 32; off > 0; off >>= 1) {
      float od = __shfl_xor(d0, off);
      int oi = __shfl_xor(i0, off);
      int ol = __shfl_xor(l0, off);
      if (od < d0 || (od == d0 && oi < i0)) { d0 = od; i0 = oi; l0 = ol; }
    }
    if (lane == r) keep = i0;   // round r's winner is the r-th nearest
    if (lane == l0) {           // winner lane pops its head
#pragma unroll
      for (int i = 0; i < K_NN - 1; ++i) { hd[i] = hd[i + 1]; hi[i] = hi[i + 1]; }
      hd[K_NN - 1] = 3.4e38f;
      hi[K_NN - 1] = 0x7fffffff;
    }
  }
  if (active && lane < K_NN) knn_out[m * K_NN + lane] = keep;
}

// -------- gather + LayerNorm + Linear + maxpool: one block per center --------
__global__ __launch_bounds__(128) void head_kernel(
    const float* __restrict__ feats, const int* __restrict__ knn,
    const float* __restrict__ lnw, const float* __restrict__ lnb,
    const float* __restrict__ W, float* __restrict__ out,
    float* __restrict__ noff) {
  const int m = blockIdx.x;
  const int t = threadIdx.x;
  __shared__ float g[K_NN][68];  // +4 pad: conflict-free LN row reads
  __shared__ float mu_s[K_NN], rs_s[K_NN];

  // gather 16 rows x 64 ch with float4 (256 quads / 128 threads = 2 each)
  for (int q = t; q < 256; q += 128) {
    int k = q >> 4, c4 = q & 15;
    int src = knn[m * K_NN + k];
    float4 v = ((const float4*)(feats + (size_t)src * C_IN))[c4];
    g[k][c4 * 4 + 0] = v.x;
    g[k][c4 * 4 + 1] = v.y;
    g[k][c4 * 4 + 2] = v.z;
    g[k][c4 * 4 + 3] = v.w;
  }
  __syncthreads();
  if (t < K_NN) {
    float s = 0.f;
    for (int c = 0; c < C_IN; ++c) s += g[t][c];
    float mu = s * (1.0f / 64.0f);
    float v = 0.f;
    for (int c = 0; c < C_IN; ++c) {
      float d = g[t][c] - mu;
      v += d * d;
    }
    v *= (1.0f / 64.0f);
    mu_s[t] = mu;
    rs_s[t] = rsqrtf(v + 1e-5f);
  }
  __syncthreads();
  for (int q = t; q < K_NN * C_IN; q += 128) {
    int k = q >> 6, c = q & 63;
    g[k][c] = (g[k][c] - mu_s[k]) * rs_s[k] * lnw[c] + lnb[c];
  }
  __syncthreads();
  // thread t owns output channel o=t: acc[k] += gn[k][c] * W[c][t]
  float acc[K_NN];
#pragma unroll
  for (int k = 0; k < K_NN; ++k) acc[k] = 0.f;
  for (int c = 0; c < C_IN; ++c) {
    float w = W[c * C_OUT + t];
#pragma unroll
    for (int k = 0; k < K_NN; ++k) acc[k] = fmaf(g[k][c], w, acc[k]);
  }
  float mx = acc[0];
#pragma unroll
  for (int k = 1; k < K_NN; ++k) mx = fmaxf(mx, acc[k]);
  out[(size_t)m * C_OUT + t] = mx;

  if (m == 0 && t == 0) noff[0] = (float)M_SAMPLES;  // buffer is read as f32
}

extern "C" void kernel_launch(void* const* d_in, const int* in_sizes, int n_in,
                              void* d_out, int out_size, void* d_ws,
                              size_t ws_size, hipStream_t stream) {
  const float* feats = (const float*)d_in[0];  // [40000,64]
  const float* xyz = (const float*)d_in[1];    // [40000,3]
  // d_in[2] = offset (single cloud, unused)
  const float* lnw = (const float*)d_in[3];  // [64]
  const float* lnb = (const float*)d_in[4];  // [64]
  const float* W = (const float*)d_in[5];    // [64,128]

  float* out = (float*)d_out;                       // [M,128]
  float* nxyz = out + (size_t)M_SAMPLES * C_OUT;    // [M,3]
  float* noff = nxyz + (size_t)M_SAMPLES * 3;       // [1]
  int* knn = (int*)d_ws;                            // [M,16] ints

  fps_kernel<<<1, FPS_THREADS, 0, stream>>>(xyz, nxyz);
  knn_kernel<<<(M_SAMPLES + 3) / 4, 256, 0, stream>>>(xyz, nxyz, knn);
  head_kernel<<<M_SAMPLES, 128, 0, stream>>>(feats, knn, lnw, lnb, W, out,
                                             noff);
}

// Round 2
// 27957.037 us; speedup vs baseline: 3.6673x; 3.6673x over previous
//
#include <hip/hip_runtime.h>

#define N_PTS 40000
#define C_IN 64
#define C_OUT 128
#define K_NN 16
#define M_SAMPLES 10001   // int(40000*0.25)+1

#define NGROUPS 625       // 40000 / 64, exact
#define GRID_DIM 8        // 8x8x8 buckets over [0,10)^3

// Exact reference arithmetic: (dx*dx + dy*dy) + dz*dz, no FMA contraction.
__device__ __forceinline__ float dist3_exact(float dx, float dy, float dz) {
#pragma clang fp contract(off)
  return (dx * dx + dy * dy) + dz * dz;
}

__device__ __forceinline__ int cell_of(float x, float y, float z) {
  int cx = min(GRID_DIM - 1, max(0, (int)(x * 0.8f)));
  int cy = min(GRID_DIM - 1, max(0, (int)(y * 0.8f)));
  int cz = min(GRID_DIM - 1, max(0, (int)(z * 0.8f)));
  return (cx << 6) | (cy << 3) | cz;
}

// ---------------- bucketing prologue ----------------
__global__ void hist_kernel(const float* __restrict__ xyz, int* __restrict__ hist) {
  int p = blockIdx.x * 256 + threadIdx.x;
  if (p < N_PTS) {
    int c = cell_of(xyz[3 * p], xyz[3 * p + 1], xyz[3 * p + 2]);
    atomicAdd(&hist[c], 1);
  }
}

__global__ __launch_bounds__(512) void scan_kernel(const int* __restrict__ hist,
                                                   int* __restrict__ cursor) {
  __shared__ int tmp[512];
  int t = threadIdx.x;
  tmp[t] = hist[t];
  __syncthreads();
  for (int off = 1; off < 512; off <<= 1) {
    int v = tmp[t];
    int u = (t >= off) ? tmp[t - off] : 0;
    __syncthreads();
    tmp[t] = v + u;
    __syncthreads();
  }
  cursor[t] = (t == 0) ? 0 : tmp[t - 1];
}

__global__ void scatter_kernel(const float* __restrict__ xyz, int* __restrict__ cursor,
                               float* __restrict__ gx, float* __restrict__ gy,
                               float* __restrict__ gz, int* __restrict__ gidx) {
  int p = blockIdx.x * 256 + threadIdx.x;
  if (p < N_PTS) {
    float x = xyz[3 * p], y = xyz[3 * p + 1], z = xyz[3 * p + 2];
    int c = cell_of(x, y, z);
    int pos = atomicAdd(&cursor[c], 1);
    gx[pos] = x; gy[pos] = y; gz[pos] = z; gidx[pos] = p;
  }
}

__global__ __launch_bounds__(64) void bbox_kernel(const float* __restrict__ gx,
                                                  const float* __restrict__ gy,
                                                  const float* __restrict__ gz,
                                                  float* __restrict__ bbox) {
  int g = blockIdx.x, lane = threadIdx.x;
  float x = gx[g * 64 + lane], y = gy[g * 64 + lane], z = gz[g * 64 + lane];
  float lox = x, hix = x, loy = y, hiy = y, loz = z, hiz = z;
#pragma unroll
  for (int off = 32; off > 0; off >>= 1) {
    lox = fminf(lox, __shfl_xor(lox, off)); hix = fmaxf(hix, __shfl_xor(hix, off));
    loy = fminf(loy, __shfl_xor(loy, off)); hiy = fmaxf(hiy, __shfl_xor(hiy, off));
    loz = fminf(loz, __shfl_xor(loz, off)); hiz = fmaxf(hiz, __shfl_xor(hiz, off));
  }
  if (lane == 0) {
    bbox[g * 6 + 0] = lox; bbox[g * 6 + 1] = hix;
    bbox[g * 6 + 2] = loy; bbox[g * 6 + 3] = hiy;
    bbox[g * 6 + 4] = loz; bbox[g * 6 + 5] = hiz;
  }
}

// ---------------- pruned FPS: single block, 1024 threads ----------------
__global__ __launch_bounds__(1024) void fps_kernel(
    const float* __restrict__ xyz, const float* __restrict__ gx,
    const float* __restrict__ gy, const float* __restrict__ gz,
    const int* __restrict__ gidx, const float* __restrict__ bbox,
    float* __restrict__ nxyz_out) {
  // LDS budget: 160000 + 2500 + 64 + 4 + 4 + 8 + 1250 = 163830 <= 163840
  __shared__ float dist_s[N_PTS];
  __shared__ float maxv_s[NGROUPS];
  __shared__ float red_s[16];
  __shared__ int cnt_a, cnt_c;
  __shared__ int win_s[2];
  __shared__ unsigned short list_s[NGROUPS];

  const int t = threadIdx.x;
  const int lane = t & 63;
  const int wv = t >> 6;  // 0..15

  for (int i = t; i < N_PTS; i += 1024) dist_s[i] = 1e10f;
  for (int i = t; i < NGROUPS; i += 1024) maxv_s[i] = 1e10f;
  if (t == 0) { cnt_a = 0; cnt_c = 0; win_s[0] = 0x7fffffff; win_s[1] = 0x7fffffff; }
  float lx = xyz[0], ly = xyz[1], lz = xyz[2];  // center 0 = point 0
  __syncthreads();

  // cache my group's bbox in registers (thread t owns group t, t<625)
  float blox = 0.f, bhix = 0.f, bloy = 0.f, bhiy = 0.f, bloz = 0.f, bhiz = 0.f;
  if (t < NGROUPS) {
    blox = bbox[t * 6 + 0]; bhix = bbox[t * 6 + 1];
    bloy = bbox[t * 6 + 2]; bhiy = bbox[t * 6 + 3];
    bloz = bbox[t * 6 + 4]; bhiz = bbox[t * 6 + 5];
  }

  for (int s = 0; s < M_SAMPLES; ++s) {
    const int par = s & 1;
    if (t == 0) {
      nxyz_out[3 * s + 0] = lx;
      nxyz_out[3 * s + 1] = ly;
      nxyz_out[3 * s + 2] = lz;
      cnt_c = 0;                        // last read: prev iter C3 (pre-barrier5)
      win_s[1 - par] = 0x7fffffff;      // reset next iteration's winner slot
    }
    // ---- A: conservative group skip test (approx math + safety margin) ----
    bool active = false;
    if (t < NGROUPS) {
      float ex = fmaxf(fmaxf(blox - lx, lx - bhix), 0.f);
      float ey = fmaxf(fmaxf(bloy - ly, ly - bhiy), 0.f);
      float ez = fmaxf(fmaxf(bloz - lz, lz - bhiz), 0.f);
      float lb = ex * ex + ey * ey + ez * ez;
      active = !(lb * 0.99999f >= maxv_s[t]);  // skip only when provably no change
    }
    unsigned long long mask = __ballot(active);
    int base = 0;
    if (lane == 0 && mask) base = atomicAdd(&cnt_a, __popcll(mask));
    base = __shfl(base, 0);
    if (active) {
      int rank = __popcll(mask & ((1ull << lane) - 1ull));
      list_s[base + rank] = (unsigned short)t;
    }
    __syncthreads();  // barrier 1: active list complete
    // ---- B: update active groups (one wave per group, 1 point per lane) ----
    const int na = cnt_a;
    for (int i = wv; i < na; i += 16) {
      int g = list_s[i];
      int slot = g * 64 + lane;
      float x = gx[slot], y = gy[slot], z = gz[slot];
      float dx, dy, dz;
      {
#pragma clang fp contract(off)
        dx = x - lx; dy = y - ly; dz = z - lz;
      }
      float d = dist3_exact(dx, dy, dz);
      float nd = fminf(dist_s[slot], d);
      dist_s[slot] = nd;
      float mv = nd;
#pragma unroll
      for (int off = 32; off > 0; off >>= 1) mv = fmaxf(mv, __shfl_xor(mv, off));
      if (lane == 0) maxv_s[g] = mv;
    }
    __syncthreads();  // barrier 2: dist/maxv updates visible
    if (t == 0) cnt_a = 0;  // next use is next iter's A (many barriers away)
    // ---- C1: global max over group maxima ----
    float mv = (t < NGROUPS) ? maxv_s[t] : -1.0f;
#pragma unroll
    for (int off = 32; off > 0; off >>= 1) mv = fmaxf(mv, __shfl_xor(mv, off));
    if (lane == 0) red_s[wv] = mv;
    __syncthreads();  // barrier 3
    float V = red_s[0];
#pragma unroll
    for (int w = 1; w < 16; ++w) V = fmaxf(V, red_s[w]);
    // ---- C2: groups tied at V (almost always exactly one) ----
    bool cand = (t < NGROUPS) && (maxv_s[t] == V);
    mask = __ballot(cand);
    base = 0;
    if (lane == 0 && mask) base = atomicAdd(&cnt_c, __popcll(mask));
    base = __shfl(base, 0);
    if (cand) {
      int rank = __popcll(mask & ((1ull << lane) - 1ull));
      list_s[base + rank] = (unsigned short)t;
    }
    __syncthreads();  // barrier 4: candidate list complete
    // ---- C3: min original index among dist==V (exact argmax tie-break) ----
    const int nc = cnt_c;
    for (int i = wv; i < nc; i += 16) {
      int g = list_s[i];
      int slot = g * 64 + lane;
      int ci = (dist_s[slot] == V) ? gidx[slot] : 0x7fffffff;
#pragma unroll
      for (int off = 32; off > 0; off >>= 1) ci = min(ci, __shfl_xor(ci, off));
      if (lane == 0) atomicMin(&win_s[par], ci);
    }
    __syncthreads();  // barrier 5: winner final
    int bi = win_s[par];
    lx = xyz[3 * bi + 0];  // broadcast load, L1/L2-hot
    ly = xyz[3 * bi + 1];
    lz = xyz[3 * bi + 2];
  }
}

// ---------------- KNN: one wave per center ----------------
#define KNN_TILE 2048

__device__ __forceinline__ float knn_dist_exact(float sn, float cx, float cy,
                                                float cz, float x, float y,
                                                float z) {
#pragma clang fp contract(off)
  float sx = (x * x + y * y) + z * z;
  float dot = (cx * x + cy * y) + cz * z;
  return (sn - 2.0f * dot) + sx;
}

__global__ __launch_bounds__(256) void knn_kernel(
    const float* __restrict__ xyz, const float* __restrict__ nxyz,
    int* __restrict__ knn_out) {
  __shared__ float txyz[KNN_TILE * 3];
  const int lane = threadIdx.x & 63;
  const int wv = threadIdx.x >> 6;
  const int m = blockIdx.x * 4 + wv;
  const bool active = (m < M_SAMPLES);

  float cx = 0.f, cy = 0.f, cz = 0.f;
  if (active) {
    cx = nxyz[3 * m + 0]; cy = nxyz[3 * m + 1]; cz = nxyz[3 * m + 2];
  }
  float sn;
  {
#pragma clang fp contract(off)
    sn = (cx * cx + cy * cy) + cz * cz;
  }

  float hd[K_NN];
  int hi[K_NN];
#pragma unroll
  for (int i = 0; i < K_NN; ++i) { hd[i] = 3.4e38f; hi[i] = 0x7fffffff; }

  for (int base = 0; base < N_PTS; base += KNN_TILE) {
    const int cnt = min(KNN_TILE, N_PTS - base);
    __syncthreads();
    {
      const float4* src4 = (const float4*)(xyz + (size_t)base * 3);
      float4* dst4 = (float4*)txyz;
      const int n4 = (cnt * 3) >> 2;
      for (int i = threadIdx.x; i < n4; i += 256) dst4[i] = src4[i];
    }
    __syncthreads();
    for (int p = lane; p < cnt; p += 64) {
      float x = txyz[3 * p + 0], y = txyz[3 * p + 1], z = txyz[3 * p + 2];
      float d = knn_dist_exact(sn, cx, cy, cz, x, y, z);
      int gi = base + p;
      if (d < hd[K_NN - 1] || (d == hd[K_NN - 1] && gi < hi[K_NN - 1])) {
        hd[K_NN - 1] = d;
        hi[K_NN - 1] = gi;
#pragma unroll
        for (int i = K_NN - 1; i > 0; --i) {
          bool sw = (hd[i] < hd[i - 1]) ||
                    (hd[i] == hd[i - 1] && hi[i] < hi[i - 1]);
          if (sw) {
            float td = hd[i]; hd[i] = hd[i - 1]; hd[i - 1] = td;
            int ti = hi[i]; hi[i] = hi[i - 1]; hi[i - 1] = ti;
          }
        }
      }
    }
  }

  int keep = 0;
#pragma unroll 1
  for (int r = 0; r < K_NN; ++r) {
    float d0 = hd[0];
    int i0 = hi[0];
    int l0 = lane;
#pragma unroll
    for (int off = 32; off > 0; off >>= 1) {
      float od = __shfl_xor(d0, off);
      int oi = __shfl_xor(i0, off);
      int ol = __shfl_xor(l0, off);
      if (od < d0 || (od == d0 && oi < i0)) { d0 = od; i0 = oi; l0 = ol; }
    }
    if (lane == r) keep = i0;
    if (lane == l0) {
#pragma unroll
      for (int i = 0; i < K_NN - 1; ++i) { hd[i] = hd[i + 1]; hi[i] = hi[i + 1]; }
      hd[K_NN - 1] = 3.4e38f;
      hi[K_NN - 1] = 0x7fffffff;
    }
  }
  if (active && lane < K_NN) knn_out[m * K_NN + lane] = keep;
}

// -------- gather + LayerNorm + Linear + maxpool: one block per center --------
__global__ __launch_bounds__(128) void head_kernel(
    const float* __restrict__ feats, const int* __restrict__ knn,
    const float* __restrict__ lnw, const float* __restrict__ lnb,
    const float* __restrict__ W, float* __restrict__ out,
    float* __restrict__ noff) {
  const int m = blockIdx.x;
  const int t = threadIdx.x;
  __shared__ float g[K_NN][68];
  __shared__ float mu_s[K_NN], rs_s[K_NN];

  for (int q = t; q < 256; q += 128) {
    int k = q >> 4, c4 = q & 15;
    int src = knn[m * K_NN + k];
    float4 v = ((const float4*)(feats + (size_t)src * C_IN))[c4];
    g[k][c4 * 4 + 0] = v.x;
    g[k][c4 * 4 + 1] = v.y;
    g[k][c4 * 4 + 2] = v.z;
    g[k][c4 * 4 + 3] = v.w;
  }
  __syncthreads();
  if (t < K_NN) {
    float s = 0.f;
    for (int c = 0; c < C_IN; ++c) s += g[t][c];
    float mu = s * (1.0f / 64.0f);
    float v = 0.f;
    for (int c = 0; c < C_IN; ++c) {
      float d = g[t][c] - mu;
      v += d * d;
    }
    v *= (1.0f / 64.0f);
    mu_s[t] = mu;
    rs_s[t] = rsqrtf(v + 1e-5f);
  }
  __syncthreads();
  for (int q = t; q < K_NN * C_IN; q += 128) {
    int k = q >> 6, c = q & 63;
    g[k][c] = (g[k][c] - mu_s[k]) * rs_s[k] * lnw[c] + lnb[c];
  }
  __syncthreads();
  float acc[K_NN];
#pragma unroll
  for (int k = 0; k < K_NN; ++k) acc[k] = 0.f;
  for (int c = 0; c < C_IN; ++c) {
    float w = W[c * C_OUT + t];
#pragma unroll
    for (int k = 0; k < K_NN; ++k) acc[k] = fmaf(g[k][c], w, acc[k]);
  }
  float mx = acc[0];
#pragma unroll
  for (int k = 1; k < K_NN; ++k) mx = fmaxf(mx, acc[k]);
  out[(size_t)m * C_OUT + t] = mx;

  if (m == 0 && t == 0) noff[0] = (float)M_SAMPLES;
}

extern "C" void kernel_launch(void* const* d_in, const int* in_sizes, int n_in,
                              void* d_out, int out_size, void* d_ws,
                              size_t ws_size, hipStream_t stream) {
  const float* feats = (const float*)d_in[0];
  const float* xyz = (const float*)d_in[1];
  const float* lnw = (const float*)d_in[3];
  const float* lnb = (const float*)d_in[4];
  const float* W = (const float*)d_in[5];

  float* out = (float*)d_out;
  float* nxyz = out + (size_t)M_SAMPLES * C_OUT;
  float* noff = nxyz + (size_t)M_SAMPLES * 3;

  char* ws = (char*)d_ws;
  int* hist = (int*)(ws + 0);              // 512 ints
  int* cursor = (int*)(ws + 2048);         // 512 ints
  float* gx = (float*)(ws + 4096);         // 40000 f
  float* gy = (float*)(ws + 164096);       // 40000 f
  float* gz = (float*)(ws + 324096);       // 40000 f
  int* gidx = (int*)(ws + 484096);         // 40000 i
  float* bbox = (float*)(ws + 644096);     // 625*6 f
  int* knn = (int*)(ws + 659104);          // 10001*16 i

  hipMemsetAsync(hist, 0, 512 * sizeof(int), stream);
  hist_kernel<<<(N_PTS + 255) / 256, 256, 0, stream>>>(xyz, hist);
  scan_kernel<<<1, 512, 0, stream>>>(hist, cursor);
  scatter_kernel<<<(N_PTS + 255) / 256, 256, 0, stream>>>(xyz, cursor, gx, gy, gz, gidx);
  bbox_kernel<<<NGROUPS, 64, 0, stream>>>(gx, gy, gz, bbox);
  fps_kernel<<<1, 1024, 0, stream>>>(xyz, gx, gy, gz, gidx, bbox, nxyz);
  knn_kernel<<<(M_SAMPLES + 3) / 4, 256, 0, stream>>>(xyz, nxyz, knn);
  head_kernel<<<M_SAMPLES, 128, 0, stream>>>(feats, knn, lnw, lnb, W, out, noff);
}